// Round 8
// baseline (465.768 us; speedup 1.0000x reference)
//
#include <hip/hip_runtime.h>
#include <math.h>

constexpr int   NGc    = 128;
constexpr int   NCELL  = NGc * NGc;
constexpr int   NBIN   = 128 * 32;          // bin = (bx, by>>2) : 4096
constexpr float DTc    = 1e-4f;
constexpr float DXc    = 1.0f / 128.0f;
constexpr float INV_DX = 128.0f;
constexpr float P_VOLc = (DXc * 0.5f) * (DXc * 0.5f);
constexpr float P_MASSc = P_VOLc * 1.0f;
constexpr float GRAV   = 9.8f;
constexpr float STRESS_COEF = -DTc * P_VOLc * 4.0f * INV_DX * INV_DX;

// ---------------------------------------------------------------------------
// S1: bin to 4096 bins (cell-row x col-group). LDS hist + local rank ->
// key = bin<<20 | pos_in_bin.
// ---------------------------------------------------------------------------
constexpr int S1_PPT = 16;
constexpr int S1_BLK = 1024;

__global__ __launch_bounds__(1024) void bin_kernel(
    const float2* __restrict__ x, unsigned* __restrict__ key,
    unsigned* __restrict__ gcnt, int n)
{
    __shared__ unsigned hist[NBIN];
#pragma unroll
    for (int j = 0; j < NBIN / S1_BLK; j++)
        hist[threadIdx.x + j * S1_BLK] = 0;
    __syncthreads();

    int base_i = blockIdx.x * (S1_BLK * S1_PPT);
    unsigned t_arr[S1_PPT], r_arr[S1_PPT];
#pragma unroll
    for (int k = 0; k < S1_PPT; k++) {
        int i = base_i + k * S1_BLK + threadIdx.x;
        unsigned t = 0, r = 0;
        if (i < n) {
            float2 xi = x[i];
            int bx = (int)floorf(xi.x * INV_DX - 0.5f);
            int by = (int)floorf(xi.y * INV_DX - 0.5f);
            t = (unsigned)(bx * 32 + (by >> 2));
            r = atomicAdd(&hist[t], 1u);
        }
        t_arr[k] = t; r_arr[k] = r;
    }
    __syncthreads();

#pragma unroll
    for (int j = 0; j < NBIN / S1_BLK; j++) {
        int b = threadIdx.x + j * S1_BLK;
        unsigned c = hist[b];
        __syncthreads();
        hist[b] = c ? atomicAdd(&gcnt[b], c) : 0u;
        __syncthreads();
    }

#pragma unroll
    for (int k = 0; k < S1_PPT; k++) {
        int i = base_i + k * S1_BLK + threadIdx.x;
        if (i < n)
            key[i] = (t_arr[k] << 20) | (hist[t_arr[k]] + r_arr[k]);
    }
}

// ---------------------------------------------------------------------------
// S2: exclusive scan over 4096 bin counts (single block, 4/thread) + sentinel
// ---------------------------------------------------------------------------
__global__ __launch_bounds__(1024) void scan_kernel(
    const unsigned* __restrict__ gcnt, unsigned* __restrict__ binoff)
{
    __shared__ unsigned s[1024];
    int t = threadIdx.x;
    unsigned v0 = gcnt[4 * t], v1 = gcnt[4 * t + 1];
    unsigned v2 = gcnt[4 * t + 2], v3 = gcnt[4 * t + 3];
    unsigned p = v0 + v1 + v2 + v3;
    s[t] = p;
    __syncthreads();
    for (int d = 1; d < 1024; d <<= 1) {
        unsigned add = (t >= d) ? s[t - d] : 0u;
        __syncthreads();
        s[t] += add;
        __syncthreads();
    }
    unsigned base = s[t] - p;
    binoff[4 * t]     = base;
    binoff[4 * t + 1] = base + v0;
    binoff[4 * t + 2] = base + v0 + v1;
    binoff[4 * t + 3] = base + v0 + v1 + v2;
    if (t == 1023) binoff[4096] = s[1023];
}

// ---------------------------------------------------------------------------
// Stage A: NN stress. Weights read directly from global with literal-offset
// uniform indexing (SMEM-eligible); __launch_bounds__(256,2) gives the
// register allocator a 256-VGPR budget so h-arrays stay in registers.
// Scatter packed 32B record {x,y,a00,a01,a10,a11,pvx,pvy} to bin-sorted slot.
// ---------------------------------------------------------------------------
__global__ __launch_bounds__(256, 2) void stagea_kernel(
    const float2* __restrict__ x, const float2* __restrict__ v,
    const float4* __restrict__ C, const float4* __restrict__ F,
    const float* __restrict__ W1, const float* __restrict__ b1,
    const float* __restrict__ W2, const float* __restrict__ b2,
    const float* __restrict__ W3, const float* __restrict__ b3,
    const float* __restrict__ W4,
    const unsigned* __restrict__ key, const unsigned* __restrict__ binoff,
    float4* __restrict__ recs, int n)
{
    int i = blockIdx.x * 256 + threadIdx.x;
    if (i >= n) return;

    float2 xi = x[i];
    float2 vi = v[i];
    float4 Ci = C[i];
    float4 Fi = F[i];

    float Fn00 = Fi.x + DTc * (Ci.x * Fi.x + Ci.y * Fi.z);
    float Fn01 = Fi.y + DTc * (Ci.x * Fi.y + Ci.y * Fi.w);
    float Fn10 = Fi.z + DTc * (Ci.z * Fi.x + Ci.w * Fi.z);
    float Fn11 = Fi.w + DTc * (Ci.z * Fi.y + Ci.w * Fi.w);

    float Cm00 = Fn00 * Fn00 + Fn10 * Fn10;
    float Cm01 = Fn00 * Fn01 + Fn10 * Fn11;
    float Cm11 = Fn01 * Fn01 + Fn11 * Fn11;

    float tr  = Cm00 + Cm11;
    float det = Cm00 * Cm11 - Cm01 * Cm01;
    float g   = tr * tr - 4.0f * det;
    float gate = (g > 1e-8f) ? 1.0f : 0.0f;
    float delta = sqrtf(fmaxf(g, 1e-8f));
    float feat0 = 0.5f * (tr + delta);
    float feat1 = 0.5f * (tr - delta);

    float h1[16], h2[16], h3[16];
#pragma unroll
    for (int j = 0; j < 16; j++)
        h1[j] = fmaxf(W1[2 * j] * feat0 + W1[2 * j + 1] * feat1 + b1[j], 0.0f);
#pragma unroll
    for (int j = 0; j < 16; j++) {
        float a = b2[j];
#pragma unroll
        for (int kk = 0; kk < 16; kk++) a += W2[j * 16 + kk] * h1[kk];
        h2[j] = fmaxf(a, 0.0f);
    }
#pragma unroll
    for (int j = 0; j < 16; j++) {
        float a = b3[j];
#pragma unroll
        for (int kk = 0; kk < 16; kk++) a += W3[j * 16 + kk] * h2[kk];
        h3[j] = fmaxf(a, 0.0f);
    }

    float dh3[16];
#pragma unroll
    for (int j = 0; j < 16; j++) dh3[j] = (h3[j] > 0.0f) ? W4[j] : 0.0f;

    float dh2[16];
#pragma unroll
    for (int kk = 0; kk < 16; kk++) {
        float a = 0.0f;
#pragma unroll
        for (int j = 0; j < 16; j++) a += W3[j * 16 + kk] * dh3[j];
        dh2[kk] = (h2[kk] > 0.0f) ? a : 0.0f;
    }

    float dfeat0 = 0.0f, dfeat1 = 0.0f;
#pragma unroll
    for (int kk = 0; kk < 16; kk++) {
        float a = 0.0f;
#pragma unroll
        for (int j = 0; j < 16; j++) a += W2[j * 16 + kk] * dh2[j];
        float dh1k = (h1[kk] > 0.0f) ? a : 0.0f;
        dfeat0 += W1[2 * kk] * dh1k;
        dfeat1 += W1[2 * kk + 1] * dh1k;
    }

    float half_sum  = 0.5f * (dfeat0 + dfeat1);
    float half_diff = 0.5f * (dfeat0 - dfeat1);
    float inv_delta = 1.0f / delta;
    float dtr  = half_sum + half_diff * tr * inv_delta * gate;
    float ddet = half_diff * (-2.0f) * inv_delta * gate;

    float S00 = 2.0f * (dtr + ddet * Cm11);
    float S11 = 2.0f * (dtr + ddet * Cm00);
    float S01 = -2.0f * ddet * Cm01;

    float dF00 = Fn00 * S00 + Fn01 * S01;
    float dF01 = Fn00 * S01 + Fn01 * S11;
    float dF10 = Fn10 * S00 + Fn11 * S01;
    float dF11 = Fn10 * S01 + Fn11 * S11;

    float a00 = STRESS_COEF * dF00 + P_MASSc * Ci.x;
    float a01 = STRESS_COEF * dF01 + P_MASSc * Ci.y;
    float a10 = STRESS_COEF * dF10 + P_MASSc * Ci.z;
    float a11 = STRESS_COEF * dF11 + P_MASSc * Ci.w;

    unsigned k = key[i];
    unsigned pos = binoff[k >> 20] + (k & 0xFFFFFu);

    recs[2 * (size_t)pos]     = make_float4(xi.x, xi.y, a00, a01);
    recs[2 * (size_t)pos + 1] = make_float4(a10, a11, P_MASSc * vi.x, P_MASSc * vi.y);
}

// ---------------------------------------------------------------------------
// Gather-form grid build, 8 nodes per wave. Each lane accumulates into its
// private 25-float LDS slice (8 nodes x 3 comps, padded); per-wave lane
// reduction; fused grid update. Records are read ~4.5x instead of 18x.
// ---------------------------------------------------------------------------
__global__ __launch_bounds__(256) void grid_gather_kernel(
    const float4* __restrict__ recs, const unsigned* __restrict__ binoff,
    float2* __restrict__ gv)
{
    __shared__ float lds[4 * 64 * 25];          // 25.6 KB: wave-private slices

    int wid  = threadIdx.x >> 6;
    int lane = threadIdx.x & 63;
    int w    = blockIdx.x * 4 + wid;            // 512 blocks * 4 waves = 2048
    int base = w * 8;                           // 8 consecutive nodes, one row
    int gi   = base >> 7;
    int gj0  = base & 127;

    float* slice = lds + (wid * 64 + lane) * 25;
#pragma unroll
    for (int t = 0; t < 25; t++) slice[t] = 0.0f;

    int c0 = max(gj0 - 2, 0) >> 2;
    int c1 = (gj0 + 7) >> 2;

#pragma unroll
    for (int r = 0; r < 3; r++) {
        int bx = gi - 2 + r;                    // particle row; ii = gi - bx = 2-r
        if (bx < 0 || bx > 127) continue;       // wave-uniform
        int lo = (int)binoff[bx * 32 + c0];
        int hi = (int)binoff[bx * 32 + c1 + 1];
        for (int k = lo + lane; k < hi; k += 64) {
            float4 r0 = recs[2 * (size_t)k];
            float4 r1 = recs[2 * (size_t)k + 1];

            float py = r0.y * INV_DX;
            int   by = (int)floorf(py - 0.5f);
            float fy = py - (float)by;
            float fx = r0.x * INV_DX - (float)bx;

            float wx;
            if (r == 0)      wx = 0.5f * (fx - 0.5f) * (fx - 0.5f);   // ii = 2
            else if (r == 1) wx = 0.75f - (fx - 1.0f) * (fx - 1.0f);  // ii = 1
            else             wx = 0.5f * (1.5f - fx) * (1.5f - fx);   // ii = 0

            float wys[3] = {0.5f * (1.5f - fy) * (1.5f - fy),
                            0.75f - (fy - 1.0f) * (fy - 1.0f),
                            0.5f * (fy - 0.5f) * (fy - 0.5f)};

            float dxp = (float)gi * DXc - r0.x;
#pragma unroll
            for (int jj = 0; jj < 3; jj++) {
                int gjn = by + jj;
                int t   = gjn - gj0;
                if (t >= 0 && t < 8) {
                    float wt  = wx * wys[jj];
                    float dyp = (float)gjn * DXc - r0.y;
                    atomicAdd(slice + t * 3 + 0, wt * (r1.z + r0.z * dxp + r0.w * dyp));
                    atomicAdd(slice + t * 3 + 1, wt * (r1.w + r1.x * dxp + r1.y * dyp));
                    atomicAdd(slice + t * 3 + 2, wt * P_MASSc);
                }
            }
        }
    }
    __syncthreads();

    // per-wave reduction over the 64 lane-slices: lane l<24 owns (t=l/3, c=l%3)
    float tot = 0.0f;
    if (lane < 24) {
        const float* wbase = lds + wid * 64 * 25;
        for (int i2 = 0; i2 < 64; i2++) tot += wbase[i2 * 25 + lane];
    }

    float vx = __shfl(tot, 3 * lane,     64);
    float vy = __shfl(tot, 3 * lane + 1, 64);
    float m  = __shfl(tot, 3 * lane + 2, 64);

    if (lane < 8) {
        int gj = gj0 + lane;
        if (m > 0.0f) {
            float inv_m = 1.0f / m;
            vx *= inv_m;
            vy *= inv_m;
        }
        vy -= DTc * GRAV;
        if (gi < 3)        vx = fmaxf(vx, 0.0f);
        if (gi >= NGc - 3) vx = fminf(vx, 0.0f);
        if (gj < 3)        vy = fmaxf(vy, 0.0f);
        if (gj >= NGc - 3) vy = fminf(vy, 0.0f);
        gv[base + lane] = make_float2(vx, vy);
    }
}

// ---------------------------------------------------------------------------
// G2P (+ Fnew recompute and write, coalesced)
// ---------------------------------------------------------------------------
__global__ __launch_bounds__(256) void g2p_kernel(
    const float2* __restrict__ x, const float2* __restrict__ v,
    const float4* __restrict__ C, const float4* __restrict__ F,
    const int* __restrict__ material, const float* __restrict__ Jp,
    const float2* __restrict__ gv,
    float2* __restrict__ out_x, float2* __restrict__ out_v,
    float4* __restrict__ out_C, float4* __restrict__ out_F,
    float* __restrict__ out_mat, float* __restrict__ out_Jp, int n)
{
    int i = blockIdx.x * 256 + threadIdx.x;
    if (i >= n) return;

    float2 xi = x[i];
    float2 vi = v[i];
    float4 Ci = C[i];
    float4 Fi = F[i];

    float Fn00 = Fi.x + DTc * (Ci.x * Fi.x + Ci.y * Fi.z);
    float Fn01 = Fi.y + DTc * (Ci.x * Fi.y + Ci.y * Fi.w);
    float Fn10 = Fi.z + DTc * (Ci.z * Fi.x + Ci.w * Fi.z);
    float Fn11 = Fi.w + DTc * (Ci.z * Fi.y + Ci.w * Fi.w);

    float px = xi.x * INV_DX, py = xi.y * INV_DX;
    int   bx = (int)floorf(px - 0.5f);
    int   by = (int)floorf(py - 0.5f);
    float fx = px - (float)bx;
    float fy = py - (float)by;
    float wxs[3] = {0.5f * (1.5f - fx) * (1.5f - fx),
                    0.75f - (fx - 1.0f) * (fx - 1.0f),
                    0.5f * (fx - 0.5f) * (fx - 0.5f)};
    float wys[3] = {0.5f * (1.5f - fy) * (1.5f - fy),
                    0.75f - (fy - 1.0f) * (fy - 1.0f),
                    0.5f * (fy - 0.5f) * (fy - 0.5f)};

    float accvx = 0.0f, accvy = 0.0f;
    float accC00 = 0.0f, accC01 = 0.0f, accC10 = 0.0f, accC11 = 0.0f;

#pragma unroll
    for (int ii = 0; ii < 3; ii++) {
        float gxx = (float)(bx + ii) * DXc;
#pragma unroll
        for (int jj = 0; jj < 3; jj++) {
            float wt = wxs[ii] * wys[jj];
            float2 gvn = gv[(bx + ii) * NGc + (by + jj)];
            float gxy = (float)(by + jj) * DXc;
            accvx  += wt * gvn.x;
            accvy  += wt * gvn.y;
            accC00 += wt * gvn.x * gxx;
            accC01 += wt * gvn.x * gxy;
            accC10 += wt * gvn.y * gxx;
            accC11 += wt * gvn.y * gxy;
        }
    }

    const float k4 = 4.0f * INV_DX * INV_DX;
    out_x[i]   = make_float2(xi.x + DTc * vi.x, xi.y + DTc * vi.y);
    out_v[i]   = make_float2(accvx, accvy);
    out_C[i]   = make_float4(k4 * (accC00 - accvx * xi.x),
                             k4 * (accC01 - accvx * xi.y),
                             k4 * (accC10 - accvy * xi.x),
                             k4 * (accC11 - accvy * xi.y));
    out_F[i]   = make_float4(Fn00, Fn01, Fn10, Fn11);
    out_mat[i] = (float)material[i];
    out_Jp[i]  = Jp[i];
}

// ---------------------------------------------------------------------------
extern "C" void kernel_launch(void* const* d_in, const int* in_sizes, int n_in,
                              void* d_out, int out_size, void* d_ws, size_t ws_size,
                              hipStream_t stream)
{
    const float2* x  = (const float2*)d_in[0];
    const float2* v  = (const float2*)d_in[1];
    const float4* C  = (const float4*)d_in[2];
    const float4* F  = (const float4*)d_in[3];
    const int* material = (const int*)d_in[4];
    const float* Jp  = (const float*)d_in[5];
    const float* W1  = (const float*)d_in[8];
    const float* b1  = (const float*)d_in[9];
    const float* W2  = (const float*)d_in[10];
    const float* b2  = (const float*)d_in[11];
    const float* W3  = (const float*)d_in[12];
    const float* b3  = (const float*)d_in[13];
    const float* W4  = (const float*)d_in[14];

    const int n = in_sizes[0] / 2;

    // d_ws: gcnt (NBIN u32) + binoff (NBIN+1 u32) + gv (NCELL float2)
    unsigned* gcnt   = (unsigned*)d_ws;
    unsigned* binoff = gcnt + NBIN;
    float2*   gv     = (float2*)(binoff + NBIN + 1);

    float* out = (float*)d_out;
    float2* out_x   = (float2*)out;                    // 0..2N
    float2* out_v   = (float2*)(out + 2 * (size_t)n);  // 2N..4N
    float4* out_C   = (float4*)(out + 4 * (size_t)n);  // 4N..8N
    float4* out_F   = (float4*)(out + 8 * (size_t)n);  // 8N..12N
    float*  out_mat = out + 12 * (size_t)n;            // 12N..13N
    float*  out_Jp  = out + 13 * (size_t)n;            // 13N..14N

    // middle-phase scratch inside d_out (consumed before g2p overwrites):
    float4*   recs = (float4*)(out + 2 * (size_t)n);   // 8N floats: 2N..10N
    unsigned* key  = (unsigned*)out_mat;               // N u32:     12N..13N

    hipMemsetAsync(gcnt, 0, NBIN * sizeof(unsigned), stream);

    int s1_blocks = (n + S1_BLK * S1_PPT - 1) / (S1_BLK * S1_PPT);
    int blocks    = (n + 255) / 256;
    bin_kernel<<<s1_blocks, S1_BLK, 0, stream>>>(x, key, gcnt, n);
    scan_kernel<<<1, 1024, 0, stream>>>(gcnt, binoff);
    stagea_kernel<<<blocks, 256, 0, stream>>>(x, v, C, F, W1, b1, W2, b2, W3, b3, W4,
                                              key, binoff, recs, n);
    grid_gather_kernel<<<NCELL / 8 / 4, 256, 0, stream>>>(recs, binoff, gv);
    g2p_kernel<<<blocks, 256, 0, stream>>>(x, v, C, F, material, Jp, gv,
                                           out_x, out_v, out_C, out_F, out_mat, out_Jp, n);
}

// Round 9
// 295.276 us; speedup vs baseline: 1.5774x; 1.5774x over previous
//
#include <hip/hip_runtime.h>
#include <math.h>

constexpr int   NGc    = 128;
constexpr int   NCELL  = NGc * NGc;
constexpr int   NBIN   = 128 * 32;          // bin = (bx, by>>2) : 4096
constexpr float DTc    = 1e-4f;
constexpr float DXc    = 1.0f / 128.0f;
constexpr float INV_DX = 128.0f;
constexpr float P_VOLc = (DXc * 0.5f) * (DXc * 0.5f);
constexpr float P_MASSc = P_VOLc * 1.0f;
constexpr float GRAV   = 9.8f;
constexpr float STRESS_COEF = -DTc * P_VOLc * 4.0f * INV_DX * INV_DX;

// ---------------------------------------------------------------------------
// S1: bin to 4096 bins (cell-row x col-group). LDS u32 hist + local rank ->
// key = bin<<20 | pos_in_bin.  (u32 LDS atomics are fine; fp32 LDS atomics
// are ~0.3/cy/CU on gfx950 — never use them.)
// ---------------------------------------------------------------------------
constexpr int S1_PPT = 16;
constexpr int S1_BLK = 1024;

__global__ __launch_bounds__(1024) void bin_kernel(
    const float2* __restrict__ x, unsigned* __restrict__ key,
    unsigned* __restrict__ gcnt, int n)
{
    __shared__ unsigned hist[NBIN];
#pragma unroll
    for (int j = 0; j < NBIN / S1_BLK; j++)
        hist[threadIdx.x + j * S1_BLK] = 0;
    __syncthreads();

    int base_i = blockIdx.x * (S1_BLK * S1_PPT);
    unsigned t_arr[S1_PPT], r_arr[S1_PPT];
#pragma unroll
    for (int k = 0; k < S1_PPT; k++) {
        int i = base_i + k * S1_BLK + threadIdx.x;
        unsigned t = 0, r = 0;
        if (i < n) {
            float2 xi = x[i];
            int bx = (int)floorf(xi.x * INV_DX - 0.5f);
            int by = (int)floorf(xi.y * INV_DX - 0.5f);
            t = (unsigned)(bx * 32 + (by >> 2));
            r = atomicAdd(&hist[t], 1u);
        }
        t_arr[k] = t; r_arr[k] = r;
    }
    __syncthreads();

#pragma unroll
    for (int j = 0; j < NBIN / S1_BLK; j++) {
        int b = threadIdx.x + j * S1_BLK;
        unsigned c = hist[b];
        __syncthreads();
        hist[b] = c ? atomicAdd(&gcnt[b], c) : 0u;
        __syncthreads();
    }

#pragma unroll
    for (int k = 0; k < S1_PPT; k++) {
        int i = base_i + k * S1_BLK + threadIdx.x;
        if (i < n)
            key[i] = (t_arr[k] << 20) | (hist[t_arr[k]] + r_arr[k]);
    }
}

// ---------------------------------------------------------------------------
// S2: exclusive scan over 4096 bin counts (single block, 4/thread) + sentinel
// ---------------------------------------------------------------------------
__global__ __launch_bounds__(1024) void scan_kernel(
    const unsigned* __restrict__ gcnt, unsigned* __restrict__ binoff)
{
    __shared__ unsigned s[1024];
    int t = threadIdx.x;
    unsigned v0 = gcnt[4 * t], v1 = gcnt[4 * t + 1];
    unsigned v2 = gcnt[4 * t + 2], v3 = gcnt[4 * t + 3];
    unsigned p = v0 + v1 + v2 + v3;
    s[t] = p;
    __syncthreads();
    for (int d = 1; d < 1024; d <<= 1) {
        unsigned add = (t >= d) ? s[t - d] : 0u;
        __syncthreads();
        s[t] += add;
        __syncthreads();
    }
    unsigned base = s[t] - p;
    binoff[4 * t]     = base;
    binoff[4 * t + 1] = base + v0;
    binoff[4 * t + 2] = base + v0 + v1;
    binoff[4 * t + 3] = base + v0 + v1 + v2;
    if (t == 1023) binoff[4096] = s[1023];
}

// ---------------------------------------------------------------------------
// Stage A: NN stress. Weights read directly from global with literal-offset
// uniform indexing (SMEM/s_load-eligible); __launch_bounds__(256,2) gives the
// register allocator a 256-VGPR budget so h-arrays stay in registers.
// Scatter packed 32B record {x,y,a00,a01,a10,a11,pvx,pvy} to bin-sorted slot.
// ---------------------------------------------------------------------------
__global__ __launch_bounds__(256, 2) void stagea_kernel(
    const float2* __restrict__ x, const float2* __restrict__ v,
    const float4* __restrict__ C, const float4* __restrict__ F,
    const float* __restrict__ W1, const float* __restrict__ b1,
    const float* __restrict__ W2, const float* __restrict__ b2,
    const float* __restrict__ W3, const float* __restrict__ b3,
    const float* __restrict__ W4,
    const unsigned* __restrict__ key, const unsigned* __restrict__ binoff,
    float4* __restrict__ recs, int n)
{
    int i = blockIdx.x * 256 + threadIdx.x;
    if (i >= n) return;

    float2 xi = x[i];
    float2 vi = v[i];
    float4 Ci = C[i];
    float4 Fi = F[i];

    float Fn00 = Fi.x + DTc * (Ci.x * Fi.x + Ci.y * Fi.z);
    float Fn01 = Fi.y + DTc * (Ci.x * Fi.y + Ci.y * Fi.w);
    float Fn10 = Fi.z + DTc * (Ci.z * Fi.x + Ci.w * Fi.z);
    float Fn11 = Fi.w + DTc * (Ci.z * Fi.y + Ci.w * Fi.w);

    float Cm00 = Fn00 * Fn00 + Fn10 * Fn10;
    float Cm01 = Fn00 * Fn01 + Fn10 * Fn11;
    float Cm11 = Fn01 * Fn01 + Fn11 * Fn11;

    float tr  = Cm00 + Cm11;
    float det = Cm00 * Cm11 - Cm01 * Cm01;
    float g   = tr * tr - 4.0f * det;
    float gate = (g > 1e-8f) ? 1.0f : 0.0f;
    float delta = sqrtf(fmaxf(g, 1e-8f));
    float feat0 = 0.5f * (tr + delta);
    float feat1 = 0.5f * (tr - delta);

    float h1[16], h2[16], h3[16];
#pragma unroll
    for (int j = 0; j < 16; j++)
        h1[j] = fmaxf(W1[2 * j] * feat0 + W1[2 * j + 1] * feat1 + b1[j], 0.0f);
#pragma unroll
    for (int j = 0; j < 16; j++) {
        float a = b2[j];
#pragma unroll
        for (int kk = 0; kk < 16; kk++) a += W2[j * 16 + kk] * h1[kk];
        h2[j] = fmaxf(a, 0.0f);
    }
#pragma unroll
    for (int j = 0; j < 16; j++) {
        float a = b3[j];
#pragma unroll
        for (int kk = 0; kk < 16; kk++) a += W3[j * 16 + kk] * h2[kk];
        h3[j] = fmaxf(a, 0.0f);
    }

    float dh3[16];
#pragma unroll
    for (int j = 0; j < 16; j++) dh3[j] = (h3[j] > 0.0f) ? W4[j] : 0.0f;

    float dh2[16];
#pragma unroll
    for (int kk = 0; kk < 16; kk++) {
        float a = 0.0f;
#pragma unroll
        for (int j = 0; j < 16; j++) a += W3[j * 16 + kk] * dh3[j];
        dh2[kk] = (h2[kk] > 0.0f) ? a : 0.0f;
    }

    float dfeat0 = 0.0f, dfeat1 = 0.0f;
#pragma unroll
    for (int kk = 0; kk < 16; kk++) {
        float a = 0.0f;
#pragma unroll
        for (int j = 0; j < 16; j++) a += W2[j * 16 + kk] * dh2[j];
        float dh1k = (h1[kk] > 0.0f) ? a : 0.0f;
        dfeat0 += W1[2 * kk] * dh1k;
        dfeat1 += W1[2 * kk + 1] * dh1k;
    }

    float half_sum  = 0.5f * (dfeat0 + dfeat1);
    float half_diff = 0.5f * (dfeat0 - dfeat1);
    float inv_delta = 1.0f / delta;
    float dtr  = half_sum + half_diff * tr * inv_delta * gate;
    float ddet = half_diff * (-2.0f) * inv_delta * gate;

    float S00 = 2.0f * (dtr + ddet * Cm11);
    float S11 = 2.0f * (dtr + ddet * Cm00);
    float S01 = -2.0f * ddet * Cm01;

    float dF00 = Fn00 * S00 + Fn01 * S01;
    float dF01 = Fn00 * S01 + Fn01 * S11;
    float dF10 = Fn10 * S00 + Fn11 * S01;
    float dF11 = Fn10 * S01 + Fn11 * S11;

    float a00 = STRESS_COEF * dF00 + P_MASSc * Ci.x;
    float a01 = STRESS_COEF * dF01 + P_MASSc * Ci.y;
    float a10 = STRESS_COEF * dF10 + P_MASSc * Ci.z;
    float a11 = STRESS_COEF * dF11 + P_MASSc * Ci.w;

    unsigned k = key[i];
    unsigned pos = binoff[k >> 20] + (k & 0xFFFFFu);

    recs[2 * (size_t)pos]     = make_float4(xi.x, xi.y, a00, a01);
    recs[2 * (size_t)pos + 1] = make_float4(a10, a11, P_MASSc * vi.x, P_MASSc * vi.y);
}

// ---------------------------------------------------------------------------
// Gather-form grid build (proven R6/R7 form): one wave per grid node, register
// accumulate, butterfly reduce, fused grid update. No atomics, no LDS.
// ---------------------------------------------------------------------------
__global__ __launch_bounds__(256) void grid_gather_kernel(
    const float4* __restrict__ recs, const unsigned* __restrict__ binoff,
    float2* __restrict__ gv)
{
    int wid  = threadIdx.x >> 6;
    int lane = threadIdx.x & 63;
    int node = blockIdx.x * 4 + wid;
    int gi = node >> 7;
    int gj = node & 127;

    const float gxx = (float)gi * DXc;
    const float gxy = (float)gj * DXc;

    float accx = 0.0f, accy = 0.0f, accm = 0.0f;

    int c0 = max(gj - 2, 0) >> 2;
    int c1 = gj >> 2;

#pragma unroll
    for (int r = 0; r < 3; r++) {
        int bx = gi - 2 + r;
        if (bx < 0 || bx > 127) continue;     // wave-uniform
        int lo = (int)binoff[bx * 32 + c0];
        int hi = (int)binoff[bx * 32 + c1 + 1];
        for (int k = lo + lane; k < hi; k += 64) {
            float4 r0 = recs[2 * (size_t)k];
            float4 r1 = recs[2 * (size_t)k + 1];

            float py = r0.y * INV_DX;
            int   by = (int)floorf(py - 0.5f);
            int   jj = gj - by;
            bool  ok = (jj >= 0) && (jj <= 2);

            float fy = py - (float)by;
            float fx = r0.x * INV_DX - (float)bx;

            float wx;
            if (r == 0)      wx = 0.5f * (fx - 0.5f) * (fx - 0.5f);   // ii = 2
            else if (r == 1) wx = 0.75f - (fx - 1.0f) * (fx - 1.0f);  // ii = 1
            else             wx = 0.5f * (1.5f - fx) * (1.5f - fx);   // ii = 0

            float wy0 = 0.5f * (1.5f - fy) * (1.5f - fy);
            float wy1 = 0.75f - (fy - 1.0f) * (fy - 1.0f);
            float wy2 = 0.5f * (fy - 0.5f) * (fy - 0.5f);
            float wy = (jj == 0) ? wy0 : ((jj == 1) ? wy1 : wy2);

            float wt = ok ? (wx * wy) : 0.0f;
            float dxp = gxx - r0.x;
            float dyp = gxy - r0.y;
            accx += wt * (r1.z + r0.z * dxp + r0.w * dyp);
            accy += wt * (r1.w + r1.x * dxp + r1.y * dyp);
            accm += wt * P_MASSc;
        }
    }

#pragma unroll
    for (int off = 32; off >= 1; off >>= 1) {
        accx += __shfl_xor(accx, off, 64);
        accy += __shfl_xor(accy, off, 64);
        accm += __shfl_xor(accm, off, 64);
    }

    if (lane == 0) {
        float vx = accx, vy = accy;
        if (accm > 0.0f) {
            float inv_m = 1.0f / accm;
            vx *= inv_m;
            vy *= inv_m;
        }
        vy -= DTc * GRAV;
        if (gi < 3)        vx = fmaxf(vx, 0.0f);
        if (gi >= NGc - 3) vx = fminf(vx, 0.0f);
        if (gj < 3)        vy = fmaxf(vy, 0.0f);
        if (gj >= NGc - 3) vy = fminf(vy, 0.0f);
        gv[node] = make_float2(vx, vy);
    }
}

// ---------------------------------------------------------------------------
// G2P (+ Fnew recompute and write, coalesced)
// ---------------------------------------------------------------------------
__global__ __launch_bounds__(256) void g2p_kernel(
    const float2* __restrict__ x, const float2* __restrict__ v,
    const float4* __restrict__ C, const float4* __restrict__ F,
    const int* __restrict__ material, const float* __restrict__ Jp,
    const float2* __restrict__ gv,
    float2* __restrict__ out_x, float2* __restrict__ out_v,
    float4* __restrict__ out_C, float4* __restrict__ out_F,
    float* __restrict__ out_mat, float* __restrict__ out_Jp, int n)
{
    int i = blockIdx.x * 256 + threadIdx.x;
    if (i >= n) return;

    float2 xi = x[i];
    float2 vi = v[i];
    float4 Ci = C[i];
    float4 Fi = F[i];

    float Fn00 = Fi.x + DTc * (Ci.x * Fi.x + Ci.y * Fi.z);
    float Fn01 = Fi.y + DTc * (Ci.x * Fi.y + Ci.y * Fi.w);
    float Fn10 = Fi.z + DTc * (Ci.z * Fi.x + Ci.w * Fi.z);
    float Fn11 = Fi.w + DTc * (Ci.z * Fi.y + Ci.w * Fi.w);

    float px = xi.x * INV_DX, py = xi.y * INV_DX;
    int   bx = (int)floorf(px - 0.5f);
    int   by = (int)floorf(py - 0.5f);
    float fx = px - (float)bx;
    float fy = py - (float)by;
    float wxs[3] = {0.5f * (1.5f - fx) * (1.5f - fx),
                    0.75f - (fx - 1.0f) * (fx - 1.0f),
                    0.5f * (fx - 0.5f) * (fx - 0.5f)};
    float wys[3] = {0.5f * (1.5f - fy) * (1.5f - fy),
                    0.75f - (fy - 1.0f) * (fy - 1.0f),
                    0.5f * (fy - 0.5f) * (fy - 0.5f)};

    float accvx = 0.0f, accvy = 0.0f;
    float accC00 = 0.0f, accC01 = 0.0f, accC10 = 0.0f, accC11 = 0.0f;

#pragma unroll
    for (int ii = 0; ii < 3; ii++) {
        float gxx = (float)(bx + ii) * DXc;
#pragma unroll
        for (int jj = 0; jj < 3; jj++) {
            float wt = wxs[ii] * wys[jj];
            float2 gvn = gv[(bx + ii) * NGc + (by + jj)];
            float gxy = (float)(by + jj) * DXc;
            accvx  += wt * gvn.x;
            accvy  += wt * gvn.y;
            accC00 += wt * gvn.x * gxx;
            accC01 += wt * gvn.x * gxy;
            accC10 += wt * gvn.y * gxx;
            accC11 += wt * gvn.y * gxy;
        }
    }

    const float k4 = 4.0f * INV_DX * INV_DX;
    out_x[i]   = make_float2(xi.x + DTc * vi.x, xi.y + DTc * vi.y);
    out_v[i]   = make_float2(accvx, accvy);
    out_C[i]   = make_float4(k4 * (accC00 - accvx * xi.x),
                             k4 * (accC01 - accvx * xi.y),
                             k4 * (accC10 - accvy * xi.x),
                             k4 * (accC11 - accvy * xi.y));
    out_F[i]   = make_float4(Fn00, Fn01, Fn10, Fn11);
    out_mat[i] = (float)material[i];
    out_Jp[i]  = Jp[i];
}

// ---------------------------------------------------------------------------
extern "C" void kernel_launch(void* const* d_in, const int* in_sizes, int n_in,
                              void* d_out, int out_size, void* d_ws, size_t ws_size,
                              hipStream_t stream)
{
    const float2* x  = (const float2*)d_in[0];
    const float2* v  = (const float2*)d_in[1];
    const float4* C  = (const float4*)d_in[2];
    const float4* F  = (const float4*)d_in[3];
    const int* material = (const int*)d_in[4];
    const float* Jp  = (const float*)d_in[5];
    const float* W1  = (const float*)d_in[8];
    const float* b1  = (const float*)d_in[9];
    const float* W2  = (const float*)d_in[10];
    const float* b2  = (const float*)d_in[11];
    const float* W3  = (const float*)d_in[12];
    const float* b3  = (const float*)d_in[13];
    const float* W4  = (const float*)d_in[14];

    const int n = in_sizes[0] / 2;

    // d_ws: gcnt (NBIN u32) + binoff (NBIN+1 u32) + gv (NCELL float2)
    unsigned* gcnt   = (unsigned*)d_ws;
    unsigned* binoff = gcnt + NBIN;
    float2*   gv     = (float2*)(binoff + NBIN + 1);

    float* out = (float*)d_out;
    float2* out_x   = (float2*)out;                    // 0..2N
    float2* out_v   = (float2*)(out + 2 * (size_t)n);  // 2N..4N
    float4* out_C   = (float4*)(out + 4 * (size_t)n);  // 4N..8N
    float4* out_F   = (float4*)(out + 8 * (size_t)n);  // 8N..12N
    float*  out_mat = out + 12 * (size_t)n;            // 12N..13N
    float*  out_Jp  = out + 13 * (size_t)n;            // 13N..14N

    // middle-phase scratch inside d_out (consumed before g2p overwrites):
    float4*   recs = (float4*)(out + 2 * (size_t)n);   // 8N floats: 2N..10N
    unsigned* key  = (unsigned*)out_mat;               // N u32:     12N..13N

    hipMemsetAsync(gcnt, 0, NBIN * sizeof(unsigned), stream);

    int s1_blocks = (n + S1_BLK * S1_PPT - 1) / (S1_BLK * S1_PPT);
    int blocks    = (n + 255) / 256;
    bin_kernel<<<s1_blocks, S1_BLK, 0, stream>>>(x, key, gcnt, n);
    scan_kernel<<<1, 1024, 0, stream>>>(gcnt, binoff);
    stagea_kernel<<<blocks, 256, 0, stream>>>(x, v, C, F, W1, b1, W2, b2, W3, b3, W4,
                                              key, binoff, recs, n);
    grid_gather_kernel<<<NCELL / 4, 256, 0, stream>>>(recs, binoff, gv);
    g2p_kernel<<<blocks, 256, 0, stream>>>(x, v, C, F, material, Jp, gv,
                                           out_x, out_v, out_C, out_F, out_mat, out_Jp, n);
}